// Round 2
// baseline (91.743 us; speedup 1.0000x reference)
//
#include <hip/hip_runtime.h>
#include <hip/hip_bf16.h>

// LocationHistoryEncoder: B=256, L=512, N=50000
//   recency[b,n] = max_t { rw^(L-1-t) * valid[b,t] : loc[b,t]==n } (baseline 0)
//   freq[b,n]    = sum_t { valid[b,t] : loc[b,t]==n }
//   out[b,n]     = recency + fw * freq / max(row_max(freq), 1)
//
// One block per row (256 blocks == 256 CUs, 512 thr = 8 waves).
// Output 51.2MB fp32 -> write-BW bound (floor ~9us). Zero-fill stores are
// issued EARLY and drain during the O(L^2) dedup loop; the loop reads one
// packed int per timestep via uniform-address LDS broadcast (conflict-free).
// rec values are NOT tracked in the loop: rw^(L-1-t) is monotone in t, so
// the scatter-max is attained at an extremal valid occurrence (first/last).

constexpr int kB = 256;
constexpr int kL = 512;
constexpr int kN = 50000;

__global__ __launch_bounds__(kL, 1) void loc_hist_enc_kernel(
    const int* __restrict__ loc_seq,
    const int* __restrict__ mask,
    const float* __restrict__ rw_p,
    const float* __restrict__ fw_p,
    float* __restrict__ out)
{
    const int b = blockIdx.x;
    const int t = threadIdx.x;              // == timestep; blockDim.x == kL

    __shared__ int   s_pk[kL];              // loc | (valid<<16); loc < 65536
    __shared__ float s_red[kL / 64];
    __shared__ float s_mf;

    const float rw = rw_p[0];
    const float fw = fw_p[0];

    const int loc = loc_seq[b * kL + t];
    const int v   = mask[b * kL + t];       // 0 or 1
    s_pk[t] = loc | (v << 16);
    __syncthreads();

    // ---- Zero-fill this row; stores issue now, retire during the dedup loop.
    // kN % 4 == 0; row base (b*kN floats) is 16B-aligned.
    float4* __restrict__ orow = reinterpret_cast<float4*>(out + (size_t)b * kN);
    const float4 z4 = make_float4(0.f, 0.f, 0.f, 0.f);
    #pragma unroll 5
    for (int i = t; i < kN / 4; i += kL) orow[i] = z4;

    // ---- O(L^2) dedup via uniform-address LDS broadcast (no bank conflicts).
    // eq <=> (loc_j == loc) && (valid_j == 1), in a single packed compare.
    const int target = loc | (1 << 16);
    int freq = 0;
    int first = 0x7fffffff;                 // first VALID occurrence of loc
    int last  = -1;                         // last  VALID occurrence of loc
    #pragma unroll 8
    for (int j = 0; j < kL; ++j) {
        const int  pj = s_pk[j];
        const bool eq = (pj == target);
        freq += eq ? 1 : 0;
        first = min(first, eq ? j : 0x7fffffff);
        last  = eq ? j : last;
    }
    const float f = (float)freq;

    // ---- Row-wide max of freq (every location's full count is held by some
    // thread; invalid threads hold counts <= true max, so the max is exact).
    float mf = f;
    #pragma unroll
    for (int off = 32; off >= 1; off >>= 1)
        mf = fmaxf(mf, __shfl_xor(mf, off));
    if ((t & 63) == 0) s_red[t >> 6] = mf;
    __syncthreads();
    if (t == 0) {
        float m = 1.0f;                     // reference clamps max_freq >= 1
        #pragma unroll
        for (int w = 0; w < kL / 64; ++w) m = fmaxf(m, s_red[w]);
        s_mf = m;
    }
    __syncthreads();   // also drains the zero-fill stores before the scatter

    // ---- Leaders (first valid occurrence) scatter the final value.
    if (v && first == t) {
        // max over valid occurrences of rw^(L-1-t): monotone -> extremal t.
        const float rec = fmaxf(powf(rw, (float)(kL - 1 - last)),
                                powf(rw, (float)(kL - 1 - first)));
        out[(size_t)b * kN + loc] = rec + fw * (f / s_mf);
    }
}

extern "C" void kernel_launch(void* const* d_in, const int* in_sizes, int n_in,
                              void* d_out, int out_size, void* d_ws, size_t ws_size,
                              hipStream_t stream) {
    const int*   loc_seq = (const int*)d_in[0];
    const int*   mask    = (const int*)d_in[1];
    const float* rw      = (const float*)d_in[2];
    const float* fw      = (const float*)d_in[3];
    // d_in[4] = num_locations (compile-time constant kN)
    float* out = (float*)d_out;

    loc_hist_enc_kernel<<<kB, kL, 0, stream>>>(loc_seq, mask, rw, fw, out);
}

// Round 3
// 79.667 us; speedup vs baseline: 1.1516x; 1.1516x over previous
//
#include <hip/hip_runtime.h>
#include <hip/hip_bf16.h>

// LocationHistoryEncoder: B=256, L=512, N=50000
//   recency[b,n] = max_t { rw^(L-1-t) * valid[b,t] : loc[b,t]==n } (baseline 0)
//   freq[b,n]    = sum_t { valid[b,t] : loc[b,t]==n }
//   out[b,n]     = recency + fw * freq / max(row_max(freq), 1)
//
// One block per row. Output 51.2MB fp32 -> write-BW bound (floor ~9us @6.1TB/s,
// confirmed by harness fill kernels hitting 6.1 TB/s).
// R1's O(L^2) LDS-broadcast dedup measured ~30us (latency-bound serial loop);
// replaced with an O(L) LDS open-addressing hash: atomicCAS insert,
// atomicAdd freq, atomicMin/Max timestep (rec = rw^(L-1-t) is monotone in t,
// so scatter-max lives at an extremal valid occurrence; fmax of both ends is
// robust for any rw>0). rw^k lookup table removes powf from the epilogue.

constexpr int kB = 256;
constexpr int kL = 512;
constexpr int kN = 50000;
constexpr int kH = 1024;          // hash slots (power of 2, > 2*L distinct max)

__device__ __forceinline__ int hash_loc(int loc) {
    return (int)(((unsigned)loc * 2654435761u) >> 16) & (kH - 1);
}

__global__ __launch_bounds__(kL, 1) void loc_hist_enc_kernel(
    const int* __restrict__ loc_seq,
    const int* __restrict__ mask,
    const float* __restrict__ rw_p,
    const float* __restrict__ fw_p,
    float* __restrict__ out)
{
    const int b = blockIdx.x;
    const int t = threadIdx.x;            // == timestep; blockDim.x == kL

    __shared__ int   h_key[kH];           // -1 = empty
    __shared__ int   h_cnt[kH];           // valid-occurrence count
    __shared__ int   h_tmin[kH];          // min valid timestep
    __shared__ int   h_tmax[kH];          // max valid timestep
    __shared__ float s_pw[kL];            // rw^k, k = 0..L-1
    __shared__ float s_red[kL / 64];
    __shared__ float s_mf;

    const float rw = rw_p[0];
    const float fw = fw_p[0];

    // ---- Init hash table + power table (one powf per thread, front-loaded).
    #pragma unroll
    for (int s = t; s < kH; s += kL) {
        h_key[s]  = -1;
        h_cnt[s]  = 0;
        h_tmin[s] = 0x7fffffff;
        h_tmax[s] = -1;
    }
    s_pw[t] = powf(rw, (float)t);

    const int loc = loc_seq[b * kL + t];
    const int v   = mask[b * kL + t];     // 0 or 1

    // ---- Zero-fill this row; fire-and-forget stores drain during hashing.
    // kN % 4 == 0; row base (b*kN floats) is 16B-aligned.
    float4* __restrict__ orow = reinterpret_cast<float4*>(out + (size_t)b * kN);
    const float4 z4 = make_float4(0.f, 0.f, 0.f, 0.f);
    #pragma unroll 5
    for (int i = t; i < kN / 4; i += kL) orow[i] = z4;

    __syncthreads();                      // table initialized

    // ---- O(L) dedup: insert valid timesteps into the LDS hash.
    if (v) {
        int s = hash_loc(loc);
        while (true) {
            const int k = atomicCAS(&h_key[s], -1, loc);
            if (k == -1 || k == loc) break;
            s = (s + 1) & (kH - 1);
        }
        atomicAdd(&h_cnt[s], 1);
        atomicMin(&h_tmin[s], t);
        atomicMax(&h_tmax[s], t);
    }
    __syncthreads();

    // ---- Row-wide max frequency (empty slots hold 0).
    float mf = fmaxf((float)h_cnt[t], (float)h_cnt[t + kL]);
    #pragma unroll
    for (int off = 32; off >= 1; off >>= 1)
        mf = fmaxf(mf, __shfl_xor(mf, off));
    if ((t & 63) == 0) s_red[t >> 6] = mf;
    __syncthreads();
    if (t == 0) {
        float m = 1.0f;                   // reference clamps max_freq >= 1
        #pragma unroll
        for (int w = 0; w < kL / 64; ++w) m = fmaxf(m, s_red[w]);
        s_mf = m;
    }
    __syncthreads();   // also drains the zero-fill stores before the scatter

    // ---- Scatter: one write per occupied slot (distinct locations).
    const float inv_mf = s_mf;
    #pragma unroll
    for (int s = t; s < kH; s += kL) {
        const int key = h_key[s];
        if (key >= 0) {
            const float rec = fmaxf(s_pw[kL - 1 - h_tmax[s]],
                                    s_pw[kL - 1 - h_tmin[s]]);
            out[(size_t)b * kN + key] = rec + fw * ((float)h_cnt[s] / inv_mf);
        }
    }
}

extern "C" void kernel_launch(void* const* d_in, const int* in_sizes, int n_in,
                              void* d_out, int out_size, void* d_ws, size_t ws_size,
                              hipStream_t stream) {
    const int*   loc_seq = (const int*)d_in[0];
    const int*   mask    = (const int*)d_in[1];
    const float* rw      = (const float*)d_in[2];
    const float* fw      = (const float*)d_in[3];
    // d_in[4] = num_locations (compile-time constant kN)
    float* out = (float*)d_out;

    loc_hist_enc_kernel<<<kB, kL, 0, stream>>>(loc_seq, mask, rw, fw, out);
}